// Round 14
// baseline (147.681 us; speedup 1.0000x reference)
//
#include <hip/hip_runtime.h>

typedef __bf16 bf16;
typedef __bf16 bf16x8 __attribute__((ext_vector_type(8)));
typedef __bf16 bf16x4 __attribute__((ext_vector_type(4)));
typedef float f32x4 __attribute__((ext_vector_type(4)));
typedef float f32x16 __attribute__((ext_vector_type(16)));
typedef unsigned int u32;
typedef u32 u32x4 __attribute__((ext_vector_type(4)));
typedef const u32 __attribute__((address_space(1)))* gp1_t;
typedef u32 __attribute__((address_space(3)))* lp3_t;

constexpr int Hdim = 1024;
constexpr int SEQ  = 2048;
constexpr int NB   = 2;
constexpr int NHEAD = 16;
constexpr int DHEAD = 64;
constexpr int MR = NB * SEQ;   // 4096 rows
constexpr float LOG2E = 1.4426950408889634f;
constexpr float QSCALE = 0.125f * LOG2E;   // folded into Q at projection time

__device__ __forceinline__ float fexp2(float x) { return __builtin_amdgcn_exp2f(x); }

__device__ __forceinline__ void gld16(const void* g, void* l) {
  __builtin_amdgcn_global_load_lds((gp1_t)g, (lp3_t)l, 16, 0, 0);
}

__device__ __forceinline__ u32 cvtpk_bf16(float lo, float hi) {
  u32 r;
  asm("v_cvt_pk_bf16_f32 %0, %1, %2" : "=v"(r) : "v"(lo), "v"(hi));
  return r;
}

// ---------------- fused fp32 -> bf16 convert for x + weights, + scaled mask ----------------
__global__ __launch_bounds__(256) void cvt_all_k(
    const float* __restrict__ x, const float* __restrict__ Wq, const float* __restrict__ Wk,
    const float* __restrict__ Wv, const float* __restrict__ Wo, const float* __restrict__ mask,
    bf16* __restrict__ xb, bf16* __restrict__ wqkv, bf16* __restrict__ wob,
    float* __restrict__ maskS) {
  const int n8x = MR * Hdim / 8;      // 524288
  const int n8w = Hdim * Hdim / 8;    // 131072
  int i = blockIdx.x * 256 + threadIdx.x;
  if (i >= n8x + 4 * n8w) {
    int o = i - (n8x + 4 * n8w);      // [0,512)
    const float4* p = reinterpret_cast<const float4*>(mask) + (size_t)o * 2;
    float4 a = p[0], b = p[1];
    a.x *= LOG2E; a.y *= LOG2E; a.z *= LOG2E; a.w *= LOG2E;
    b.x *= LOG2E; b.y *= LOG2E; b.z *= LOG2E; b.w *= LOG2E;
    float4* q = reinterpret_cast<float4*>(maskS) + (size_t)o * 2;
    q[0] = a; q[1] = b;
    return;
  }
  const float* src;
  bf16* dst;
  int slot;
  if (i < n8x) {
    src = x; dst = xb; slot = i;
  } else {
    int j = i - n8x;
    int w = j >> 17;
    int o = j & (n8w - 1);
    if (w == 0)      { src = Wq; dst = wqkv;            }
    else if (w == 1) { src = Wk; dst = wqkv + (size_t)Hdim * Hdim;     }
    else if (w == 2) { src = Wv; dst = wqkv + (size_t)2 * Hdim * Hdim; }
    else             { src = Wo; dst = wob;             }
    slot = o;
  }
  const float4* p = reinterpret_cast<const float4*>(src) + (size_t)slot * 2;
  float4 a = p[0], b = p[1];
  bf16x8 o8;
  o8[0] = (bf16)a.x; o8[1] = (bf16)a.y; o8[2] = (bf16)a.z; o8[3] = (bf16)a.w;
  o8[4] = (bf16)b.x; o8[5] = (bf16)b.y; o8[6] = (bf16)b.z; o8[7] = (bf16)b.w;
  reinterpret_cast<bf16x8*>(dst)[slot] = o8;
}

// ---------------- fused QKV NT-GEMM: 128x128 tile, BK=64, SINGLE-buffer (m97 structure) ----------------
// 32KB LDS -> ~5 blocks/CU; the per-step vmcnt(0) drain is covered by block-level TLP.
// XCD-swizzled block mapping (768 blocks % 8 == 0).
__global__ __launch_bounds__(256) void qkv_gemm_k(
    const bf16* __restrict__ A, const bf16* __restrict__ Bw,
    const float* __restrict__ bq, const float* __restrict__ bk, const float* __restrict__ bv,
    bf16* __restrict__ Qw, bf16* __restrict__ Kw, bf16* __restrict__ VTw)
{
  __shared__ __align__(16) bf16 As[128][64];
  __shared__ __align__(16) bf16 Bs[128][64];

  const int t = threadIdx.x;
  const int lane = t & 63, wave = t >> 6;
  const int ql = lane & 15, g = lane >> 4;
  const int wr = wave >> 1, wc = wave & 1;

  // T1 XCD swizzle: hw block bid executes work-item w = (bid%8)*96 + bid/8
  const int bid = blockIdx.y * 32 + blockIdx.x;   // 768 blocks
  const int w = (bid & 7) * 96 + (bid >> 3);
  const int bx = w & 31, by = w >> 5;
  const int row0 = bx * 128;
  const int col0 = by * 128;
  const int z = by >> 3;
  const float* bias = (z == 0) ? bq : (z == 1) ? bk : bv;

  f32x4 acc[4][4] = {};

  for (int kt = 0; kt < Hdim; kt += 64) {
    __syncthreads();   // previous step's readers done
#pragma unroll
    for (int i = 0; i < 4; ++i) {
      int c = i * 256 + t;
      int r = c >> 3, o = (c & 7) << 3;
      gld16(&A[(size_t)(row0 + r) * Hdim + kt + o], (char*)&As[0][0] + c * 16);
      gld16(&Bw[(size_t)(col0 + r) * Hdim + kt + o], (char*)&Bs[0][0] + c * 16);
    }
    asm volatile("s_waitcnt vmcnt(0)" ::: "memory");
    __syncthreads();   // tile landed for all waves

#pragma unroll
    for (int kk = 0; kk < 2; ++kk) {
      bf16x8 af[4], bfr[4];
#pragma unroll
      for (int m = 0; m < 4; ++m)
        af[m] = *reinterpret_cast<const bf16x8*>(&As[wr * 64 + m * 16 + ql][kk * 32 + g * 8]);
#pragma unroll
      for (int n = 0; n < 4; ++n)
        bfr[n] = *reinterpret_cast<const bf16x8*>(&Bs[wc * 64 + n * 16 + ql][kk * 32 + g * 8]);
#pragma unroll
      for (int m = 0; m < 4; ++m)
#pragma unroll
        for (int n = 0; n < 4; ++n)
          acc[m][n] = __builtin_amdgcn_mfma_f32_16x16x32_bf16(af[m], bfr[n], acc[m][n], 0, 0, 0);
    }
  }

  const float oscale = (z == 0) ? QSCALE : 1.0f;
#pragma unroll
  for (int m = 0; m < 4; ++m) {
#pragma unroll
    for (int n = 0; n < 4; ++n) {
#pragma unroll
      for (int r = 0; r < 4; ++r) {
        int gi = row0 + wr * 64 + m * 16 + g * 4 + r;
        int gj = col0 + wc * 64 + n * 16 + ql;
        int j1 = gj & (Hdim - 1);
        float v = (acc[m][n][r] + bias[j1]) * oscale;
        int b = gi >> 11, s = gi & (SEQ - 1);
        int hh = j1 >> 6, dd = j1 & 63;
        if (z == 0)
          Qw[((size_t)(b * NHEAD + hh) * SEQ + s) * DHEAD + dd] = (bf16)v;
        else if (z == 1)
          Kw[((size_t)(b * NHEAD + hh) * SEQ + s) * DHEAD + dd] = (bf16)v;
        else
          VTw[((size_t)(b * NHEAD + hh) * DHEAD + dd) * SEQ + s] = (bf16)v;
      }
    }
  }
}

// ---------------- flash attention forward: 32x32 MFMA, in-register P (round-12 version) ----------------
// grid: (32 heads, 16 q-tiles of 128). 4 waves x 32 q-rows (q = lane&31, h = lane>>5).
__global__ __launch_bounds__(256, 3) void attn_fwd_k(
    const bf16* __restrict__ Q, const bf16* __restrict__ K,
    const bf16* __restrict__ VT, const float* __restrict__ maskS,
    bf16* __restrict__ Out)
{
  const int head = blockIdx.x;
  const int qt = blockIdx.y;
  const int b = head >> 4;
  const int hh = head & 15;
  const int t = threadIdx.x, lane = t & 63, wave = t >> 6;
  const int q = lane & 31, h = lane >> 5;

  __shared__ __align__(16) bf16 Ks[2][64][64];   // [kv][d], xor-swizzled (slot ^= row&7)
  __shared__ __align__(16) bf16 VTs[2][64][64];  // [d][kv], xor-swizzled

  const bf16* Qh  = Q  + (size_t)head * SEQ * DHEAD;
  const bf16* Kh  = K  + (size_t)head * SEQ * DHEAD;
  const bf16* VTh = VT + (size_t)head * DHEAD * SEQ;
  const float* mrow = maskS + (size_t)b * SEQ;

  const int q0w = qt * 128 + wave * 32;

  bf16x8 qf[4];
#pragma unroll
  for (int s = 0; s < 4; ++s)
    qf[s] = *reinterpret_cast<const bf16x8*>(&Qh[(size_t)(q0w + q) * DHEAD + s * 16 + 8 * h]);

  f32x16 accT[2] = {};
  f32x4 psum4 = {0.f, 0.f, 0.f, 0.f};

#pragma unroll
  for (int i = 0; i < 2; ++i) {
    int c = i * 256 + t, r = c >> 3, sp = c & 7, sl = sp ^ (r & 7);
    gld16(&Kh[(size_t)r * DHEAD + sl * 8], (char*)&Ks[0][0][0] + c * 16);
    gld16(&VTh[(size_t)r * SEQ + sl * 8], (char*)&VTs[0][0][0] + c * 16);
  }
  __syncthreads();

  for (int it = 0; it < SEQ / 64; ++it) {
    const int cur = it & 1;
    const int kb0 = it * 64;

    if (it + 1 < SEQ / 64) {
      const int nb0 = kb0 + 64;
#pragma unroll
      for (int i = 0; i < 2; ++i) {
        int c = i * 256 + t, r = c >> 3, sp = c & 7, sl = sp ^ (r & 7);
        gld16(&Kh[(size_t)(nb0 + r) * DHEAD + sl * 8], (char*)&Ks[cur ^ 1][0][0] + c * 16);
        gld16(&VTh[(size_t)r * SEQ + nb0 + sl * 8], (char*)&VTs[cur ^ 1][0][0] + c * 16);
      }
    }

    const char* ksb = (const char*)&Ks[cur][0][0];
    const char* vsb = (const char*)&VTs[cur][0][0];

    // mask as accumulator init: reg r+4s of tile tt holds kv = 32tt + r + 8s + 4h
    f32x16 sacc[2];
#pragma unroll
    for (int tt = 0; tt < 2; ++tt) {
#pragma unroll
      for (int s = 0; s < 4; ++s) {
        f32x4 m4 = *reinterpret_cast<const f32x4*>(mrow + kb0 + 32 * tt + 8 * s + 4 * h);
#pragma unroll
        for (int r = 0; r < 4; ++r) sacc[tt][s * 4 + r] = m4[r];
      }
    }

    // S^T = K * Q^T (2 kv-tiles x 4 d-steps)
    __builtin_amdgcn_s_setprio(1);
#pragma unroll
    for (int tt = 0; tt < 2; ++tt) {
      const int row = 32 * tt + q;
      const int rsw = (row & 7) << 4;
#pragma unroll
      for (int s = 0; s < 4; ++s) {
        bf16x8 kf = *reinterpret_cast<const bf16x8*>(ksb + row * 128 + ((32 * s + 16 * h) ^ rsw));
        sacc[tt] = __builtin_amdgcn_mfma_f32_32x32x16_bf16(kf, qf[s], sacc[tt], 0, 0, 0);
      }
    }
    __builtin_amdgcn_s_setprio(0);

    // exp2 (unnormalized, static-max) + per-lane partial row sums
    float pe[2][16];
#pragma unroll
    for (int tt = 0; tt < 2; ++tt)
#pragma unroll
      for (int i = 0; i < 16; ++i) {
        pe[tt][i] = fexp2(sacc[tt][i]);
        psum4[i & 3] += pe[tt][i];
      }

    // pack P to bf16 B-frags in registers. swap(dst=w0,src=w1): dst[32:63]<->src[0:31].
    u32x4 pw[4];
#pragma unroll
    for (int m = 0; m < 4; ++m) {
      const int tt = m >> 1, mi = (m & 1) * 8;
      u32 w0a = cvtpk_bf16(pe[tt][mi + 0], pe[tt][mi + 1]);
      u32 w0b = cvtpk_bf16(pe[tt][mi + 2], pe[tt][mi + 3]);
      u32 w1a = cvtpk_bf16(pe[tt][mi + 4], pe[tt][mi + 5]);
      u32 w1b = cvtpk_bf16(pe[tt][mi + 6], pe[tt][mi + 7]);
      asm("v_permlane32_swap_b32 %0, %1" : "+v"(w0a), "+v"(w1a));
      asm("v_permlane32_swap_b32 %0, %1" : "+v"(w0b), "+v"(w1b));
      pw[m][0] = w0a; pw[m][1] = w0b; pw[m][2] = w1a; pw[m][3] = w1b;
    }

    // O^T += V^T * P (2 d-tiles x 4 kv-steps)
    __builtin_amdgcn_s_setprio(1);
#pragma unroll
    for (int td = 0; td < 2; ++td) {
      const int row = 32 * td + q;
      const int rsw = (row & 7) << 4;
#pragma unroll
      for (int m = 0; m < 4; ++m) {
        bf16x8 vf = *reinterpret_cast<const bf16x8*>(vsb + row * 128 + ((32 * m + 16 * h) ^ rsw));
        bf16x8 pf = __builtin_bit_cast(bf16x8, pw[m]);
        accT[td] = __builtin_amdgcn_mfma_f32_32x32x16_bf16(vf, pf, accT[td], 0, 0, 0);
      }
    }
    __builtin_amdgcn_s_setprio(0);

    __syncthreads();
  }

  // epilogue: row-sum reduce (l <-> l^32), normalize, transpose via retired Ks buffer
  float l = (psum4[0] + psum4[1]) + (psum4[2] + psum4[3]);
  l += __shfl_xor(l, 32);
  const float inv = 1.0f / l;

  char* slab = (char*)&Ks[0][0][0] + wave * 4096;   // per-wave [32 q][64 d] bf16, swizzled
  const int qsw = (q & 7) << 4;
#pragma unroll
  for (int td = 0; td < 2; ++td)
#pragma unroll
    for (int s = 0; s < 4; ++s) {
      bf16x4 o4;
#pragma unroll
      for (int r = 0; r < 4; ++r) o4[r] = (bf16)(accT[td][s * 4 + r] * inv);
      *reinterpret_cast<bf16x4*>(slab + q * 128 + (((32 * td + 8 * s + 4 * h) * 2) ^ qsw)) = o4;
    }
  asm volatile("s_waitcnt lgkmcnt(0)" ::: "memory");
#pragma unroll
  for (int i = 0; i < 4; ++i) {
    const int row = i * 8 + (lane >> 3);
    bf16x8 v = *reinterpret_cast<const bf16x8*>(slab + row * 128 + (((lane & 7) << 4) ^ ((row & 7) << 4)));
    *reinterpret_cast<bf16x8*>(&Out[((size_t)(b * SEQ) + q0w + row) * Hdim + hh * 64 + (lane & 7) * 8]) = v;
  }
}

// ---------------- output NT-GEMM: 128x64 tile, BK=32, 3-buf counted-vmcnt pipeline ----------------
__global__ __launch_bounds__(256) void out_gemm_k(
    const bf16* __restrict__ A, const bf16* __restrict__ Bm,
    const float* __restrict__ bias, float* __restrict__ C)
{
  __shared__ __align__(16) bf16 As[3][128][32];
  __shared__ __align__(16) bf16 Bs[3][64][32];

  const int t = threadIdx.x;
  const int lane = t & 63, wave = t >> 6;
  const int ql = lane & 15, g = lane >> 4;
  const int wr = wave >> 1, wc = wave & 1;
  const int row0 = blockIdx.x * 128;
  const int col0 = blockIdx.y * 64;

  f32x4 acc[4][2] = {};

#define STAGE_OUT(buf, kt)                                                        \
  {                                                                               \
    _Pragma("unroll")                                                             \
    for (int i = 0; i < 2; ++i) {                                                 \
      int c = i * 256 + t;                                                        \
      int r = c >> 2, o = (c & 3) << 3;                                           \
      gld16(&A[(size_t)(row0 + r) * Hdim + (kt) + o], (char*)&As[buf][0][0] + c * 16); \
    }                                                                             \
    {                                                                             \
      int c = t;                                                                  \
      int r = c >> 2, o = (c & 3) << 3;                                           \
      gld16(&Bm[(size_t)(col0 + r) * Hdim + (kt) + o], (char*)&Bs[buf][0][0] + c * 16); \
    }                                                                             \
  }

  constexpr int NT = Hdim / 32;   // 32 K-steps
  STAGE_OUT(0, 0);
  STAGE_OUT(1, 32);

  int cur = 0;
  for (int it = 0; it < NT; ++it) {
    if (it + 2 < NT) {
      int stg = cur + 2; if (stg >= 3) stg -= 3;
      STAGE_OUT(stg, (it + 2) * 32);
      asm volatile("s_waitcnt vmcnt(6)" ::: "memory");
    } else if (it + 1 < NT) {
      asm volatile("s_waitcnt vmcnt(3)" ::: "memory");
    } else {
      asm volatile("s_waitcnt vmcnt(0)" ::: "memory");
    }
    __builtin_amdgcn_s_barrier();

    bf16x8 af[4], bfr[2];
#pragma unroll
    for (int m = 0; m < 4; ++m)
      af[m] = *reinterpret_cast<const bf16x8*>(&As[cur][wr * 64 + m * 16 + ql][g * 8]);
#pragma unroll
    for (int n = 0; n < 2; ++n)
      bfr[n] = *reinterpret_cast<const bf16x8*>(&Bs[cur][wc * 32 + n * 16 + ql][g * 8]);
#pragma unroll
    for (int m = 0; m < 4; ++m)
#pragma unroll
      for (int n = 0; n < 2; ++n)
        acc[m][n] = __builtin_amdgcn_mfma_f32_16x16x32_bf16(af[m], bfr[n], acc[m][n], 0, 0, 0);

    __builtin_amdgcn_s_barrier();
    cur = (cur + 1 == 3) ? 0 : cur + 1;
  }
#undef STAGE_OUT

#pragma unroll
  for (int m = 0; m < 4; ++m)
#pragma unroll
    for (int n = 0; n < 2; ++n)
#pragma unroll
      for (int r = 0; r < 4; ++r) {
        int gi = row0 + wr * 64 + m * 16 + g * 4 + r;
        int gj = col0 + wc * 32 + n * 16 + ql;
        C[(size_t)gi * Hdim + gj] = acc[m][n][r] + bias[gj];
      }
}

extern "C" void kernel_launch(void* const* d_in, const int* in_sizes, int n_in,
                              void* d_out, int out_size, void* d_ws, size_t ws_size,
                              hipStream_t stream) {
  const float* x    = (const float*)d_in[0];
  const float* mask = (const float*)d_in[1];
  const float* Wq   = (const float*)d_in[2];
  const float* bq   = (const float*)d_in[3];
  const float* Wk   = (const float*)d_in[4];
  const float* bk   = (const float*)d_in[5];
  const float* Wv   = (const float*)d_in[6];
  const float* bv   = (const float*)d_in[7];
  const float* Wo   = (const float*)d_in[8];
  const float* bo   = (const float*)d_in[9];
  float* out = (float*)d_out;

  bf16* xb   = (bf16*)d_ws;
  const size_t big = (size_t)MR * Hdim;       // 4M elems
  bf16* wqkv = xb + big;                      // [3072][1024]
  bf16* wob  = wqkv + (size_t)3 * Hdim * Hdim;
  bf16* qw   = wob + (size_t)Hdim * Hdim;
  bf16* kw   = qw + big;
  bf16* vtw  = kw + big;
  bf16* attnb = vtw + big;
  float* maskS = (float*)(attnb + big);       // [2][2048] f32, pre-scaled by log2e

  const int nslots = MR * Hdim / 8 + 4 * (Hdim * Hdim / 8) + NB * SEQ / 8;  // 1049088
  cvt_all_k<<<nslots / 256, 256, 0, stream>>>(x, Wq, Wk, Wv, Wo, mask, xb, wqkv, wob, maskS);

  qkv_gemm_k<<<dim3(32, 24), 256, 0, stream>>>(
      xb, wqkv, bq, bk, bv, qw, kw, vtw);

  attn_fwd_k<<<dim3(NB * NHEAD, SEQ / 128), 256, 0, stream>>>(qw, kw, vtw, maskS, attnb);

  out_gemm_k<<<dim3(MR / 128, Hdim / 64), 256, 0, stream>>>(attnb, wob, bo, out);
}

// Round 15
// 127.848 us; speedup vs baseline: 1.1551x; 1.1551x over previous
//
#include <hip/hip_runtime.h>

typedef __bf16 bf16;
typedef __bf16 bf16x8 __attribute__((ext_vector_type(8)));
typedef __bf16 bf16x4 __attribute__((ext_vector_type(4)));
typedef float f32x4 __attribute__((ext_vector_type(4)));
typedef float f32x16 __attribute__((ext_vector_type(16)));
typedef unsigned int u32;
typedef u32 u32x4 __attribute__((ext_vector_type(4)));
typedef const u32 __attribute__((address_space(1)))* gp1_t;
typedef u32 __attribute__((address_space(3)))* lp3_t;

constexpr int Hdim = 1024;
constexpr int SEQ  = 2048;
constexpr int NB   = 2;
constexpr int NHEAD = 16;
constexpr int DHEAD = 64;
constexpr int MR = NB * SEQ;   // 4096 rows
constexpr float LOG2E = 1.4426950408889634f;
constexpr float QSCALE = 0.125f * LOG2E;   // folded into Q at projection time

__device__ __forceinline__ float fexp2(float x) { return __builtin_amdgcn_exp2f(x); }

__device__ __forceinline__ void gld16(const void* g, void* l) {
  __builtin_amdgcn_global_load_lds((gp1_t)g, (lp3_t)l, 16, 0, 0);
}

__device__ __forceinline__ u32 cvtpk_bf16(float lo, float hi) {
  u32 r;
  asm("v_cvt_pk_bf16_f32 %0, %1, %2" : "=v"(r) : "v"(lo), "v"(hi));
  return r;
}

// ---------------- fused fp32 -> bf16 convert for x + weights, + scaled mask ----------------
__global__ __launch_bounds__(256) void cvt_all_k(
    const float* __restrict__ x, const float* __restrict__ Wq, const float* __restrict__ Wk,
    const float* __restrict__ Wv, const float* __restrict__ Wo, const float* __restrict__ mask,
    bf16* __restrict__ xb, bf16* __restrict__ wqkv, bf16* __restrict__ wob,
    float* __restrict__ maskS) {
  const int n8x = MR * Hdim / 8;      // 524288
  const int n8w = Hdim * Hdim / 8;    // 131072
  int i = blockIdx.x * 256 + threadIdx.x;
  if (i >= n8x + 4 * n8w) {
    int o = i - (n8x + 4 * n8w);      // [0,512)
    const float4* p = reinterpret_cast<const float4*>(mask) + (size_t)o * 2;
    float4 a = p[0], b = p[1];
    a.x *= LOG2E; a.y *= LOG2E; a.z *= LOG2E; a.w *= LOG2E;
    b.x *= LOG2E; b.y *= LOG2E; b.z *= LOG2E; b.w *= LOG2E;
    float4* q = reinterpret_cast<float4*>(maskS) + (size_t)o * 2;
    q[0] = a; q[1] = b;
    return;
  }
  const float* src;
  bf16* dst;
  int slot;
  if (i < n8x) {
    src = x; dst = xb; slot = i;
  } else {
    int j = i - n8x;
    int w = j >> 17;
    int o = j & (n8w - 1);
    if (w == 0)      { src = Wq; dst = wqkv;            }
    else if (w == 1) { src = Wk; dst = wqkv + (size_t)Hdim * Hdim;     }
    else if (w == 2) { src = Wv; dst = wqkv + (size_t)2 * Hdim * Hdim; }
    else             { src = Wo; dst = wob;             }
    slot = o;
  }
  const float4* p = reinterpret_cast<const float4*>(src) + (size_t)slot * 2;
  float4 a = p[0], b = p[1];
  bf16x8 o8;
  o8[0] = (bf16)a.x; o8[1] = (bf16)a.y; o8[2] = (bf16)a.z; o8[3] = (bf16)a.w;
  o8[4] = (bf16)b.x; o8[5] = (bf16)b.y; o8[6] = (bf16)b.z; o8[7] = (bf16)b.w;
  reinterpret_cast<bf16x8*>(dst)[slot] = o8;
}

// ---------------- fused QKV NT-GEMM: 128x64 tile, BK=32, 2-buf 2-phase (24KB LDS) ----------------
// grid (32, 48) = 1536 blocks -> ~5-6 blocks/CU: block-level TLP covers the per-step drain.
__global__ __launch_bounds__(256) void qkv_gemm_k(
    const bf16* __restrict__ A, const bf16* __restrict__ Bw,
    const float* __restrict__ bq, const float* __restrict__ bk, const float* __restrict__ bv,
    bf16* __restrict__ Qw, bf16* __restrict__ Kw, bf16* __restrict__ VTw)
{
  __shared__ __align__(16) bf16 As[2][128][32];
  __shared__ __align__(16) bf16 Bs[2][64][32];

  const int t = threadIdx.x;
  const int lane = t & 63, wave = t >> 6;
  const int ql = lane & 15, g = lane >> 4;
  const int wr = wave >> 1, wc = wave & 1;
  const int row0 = blockIdx.x * 128;
  const int col0 = blockIdx.y * 64;          // global over 3072
  const int z = blockIdx.y >> 4;             // 0:Q 1:K 2:V
  const float* bias = (z == 0) ? bq : (z == 1) ? bk : bv;

  f32x4 acc[4][2] = {};

#define STAGE_QKV(buf, kt)                                                        \
  {                                                                               \
    _Pragma("unroll")                                                             \
    for (int i = 0; i < 2; ++i) {                                                 \
      int c = i * 256 + t;                                                        \
      int r = c >> 2, o = (c & 3) << 3;                                           \
      gld16(&A[(size_t)(row0 + r) * Hdim + (kt) + o], (char*)&As[buf][0][0] + c * 16); \
    }                                                                             \
    {                                                                             \
      int c = t;                                                                  \
      int r = c >> 2, o = (c & 3) << 3;                                           \
      gld16(&Bw[(size_t)(col0 + r) * Hdim + (kt) + o], (char*)&Bs[buf][0][0] + c * 16); \
    }                                                                             \
  }

  STAGE_QKV(0, 0);
  asm volatile("s_waitcnt vmcnt(0)" ::: "memory");
  __builtin_amdgcn_s_barrier();

  int cur = 0;
  for (int kt = 0; kt < Hdim; kt += 32) {
    if (kt + 32 < Hdim) STAGE_QKV(cur ^ 1, kt + 32);
    bf16x8 af[4], bfr[2];
#pragma unroll
    for (int m = 0; m < 4; ++m)
      af[m] = *reinterpret_cast<const bf16x8*>(&As[cur][wr * 64 + m * 16 + ql][g * 8]);
#pragma unroll
    for (int n = 0; n < 2; ++n)
      bfr[n] = *reinterpret_cast<const bf16x8*>(&Bs[cur][wc * 32 + n * 16 + ql][g * 8]);
#pragma unroll
    for (int m = 0; m < 4; ++m)
#pragma unroll
      for (int n = 0; n < 2; ++n)
        acc[m][n] = __builtin_amdgcn_mfma_f32_16x16x32_bf16(af[m], bfr[n], acc[m][n], 0, 0, 0);
    asm volatile("s_waitcnt vmcnt(0)" ::: "memory");
    __builtin_amdgcn_s_barrier();
    cur ^= 1;
  }
#undef STAGE_QKV

  const float oscale = (z == 0) ? QSCALE : 1.0f;
#pragma unroll
  for (int m = 0; m < 4; ++m) {
#pragma unroll
    for (int n = 0; n < 2; ++n) {
#pragma unroll
      for (int r = 0; r < 4; ++r) {
        int gi = row0 + wr * 64 + m * 16 + g * 4 + r;
        int gj = col0 + wc * 32 + n * 16 + ql;
        int j1 = gj & (Hdim - 1);
        float v = (acc[m][n][r] + bias[j1]) * oscale;
        int b = gi >> 11, s = gi & (SEQ - 1);
        int hh = j1 >> 6, dd = j1 & 63;
        if (z == 0)
          Qw[((size_t)(b * NHEAD + hh) * SEQ + s) * DHEAD + dd] = (bf16)v;
        else if (z == 1)
          Kw[((size_t)(b * NHEAD + hh) * SEQ + s) * DHEAD + dd] = (bf16)v;
        else
          VTw[((size_t)(b * NHEAD + hh) * DHEAD + dd) * SEQ + s] = (bf16)v;
      }
    }
  }
}

// ---------------- flash attention forward: 32x32 MFMA, in-register P, mask-in-LDS ----------------
// grid: (32 heads, 16 q-tiles of 128). 4 waves x 32 q-rows (q = lane&31, h = lane>>5).
__global__ __launch_bounds__(256, 3) void attn_fwd_k(
    const bf16* __restrict__ Q, const bf16* __restrict__ K,
    const bf16* __restrict__ VT, const float* __restrict__ maskS,
    bf16* __restrict__ Out)
{
  const int head = blockIdx.x;
  const int qt = blockIdx.y;
  const int b = head >> 4;
  const int hh = head & 15;
  const int t = threadIdx.x, lane = t & 63, wave = t >> 6;
  const int q = lane & 31, h = lane >> 5;

  __shared__ __align__(16) bf16 Ks[2][64][64];   // [kv][d], xor-swizzled (slot ^= row&7)
  __shared__ __align__(16) bf16 VTs[2][64][64];  // [d][kv], xor-swizzled
  __shared__ __align__(16) float Ms[SEQ];        // mask row (pre-scaled), broadcast reads

  const bf16* Qh  = Q  + (size_t)head * SEQ * DHEAD;
  const bf16* Kh  = K  + (size_t)head * SEQ * DHEAD;
  const bf16* VTh = VT + (size_t)head * DHEAD * SEQ;
  const float* mrow = maskS + (size_t)b * SEQ;

  const int q0w = qt * 128 + wave * 32;

  bf16x8 qf[4];
#pragma unroll
  for (int s = 0; s < 4; ++s)
    qf[s] = *reinterpret_cast<const bf16x8*>(&Qh[(size_t)(q0w + q) * DHEAD + s * 16 + 8 * h]);

  f32x16 accT[2] = {};
  f32x4 psum4 = {0.f, 0.f, 0.f, 0.f};

#pragma unroll
  for (int i = 0; i < 2; ++i) {
    int c = i * 256 + t, r = c >> 3, sp = c & 7, sl = sp ^ (r & 7);
    gld16(&Kh[(size_t)r * DHEAD + sl * 8], (char*)&Ks[0][0][0] + c * 16);
    gld16(&VTh[(size_t)r * SEQ + sl * 8], (char*)&VTs[0][0][0] + c * 16);
  }
#pragma unroll
  for (int i = 0; i < 2; ++i) {
    int c = i * 256 + t;              // 512 x 16B = 2048 f32
    gld16(&mrow[c * 4], (char*)&Ms[0] + c * 16);
  }
  __syncthreads();

  for (int it = 0; it < SEQ / 64; ++it) {
    const int cur = it & 1;
    const int kb0 = it * 64;

    if (it + 1 < SEQ / 64) {
      const int nb0 = kb0 + 64;
#pragma unroll
      for (int i = 0; i < 2; ++i) {
        int c = i * 256 + t, r = c >> 3, sp = c & 7, sl = sp ^ (r & 7);
        gld16(&Kh[(size_t)(nb0 + r) * DHEAD + sl * 8], (char*)&Ks[cur ^ 1][0][0] + c * 16);
        gld16(&VTh[(size_t)r * SEQ + nb0 + sl * 8], (char*)&VTs[cur ^ 1][0][0] + c * 16);
      }
    }

    const char* ksb = (const char*)&Ks[cur][0][0];
    const char* vsb = (const char*)&VTs[cur][0][0];

    // mask as accumulator init, from LDS (broadcast, no vmcnt dependency)
    f32x16 sacc[2];
#pragma unroll
    for (int tt = 0; tt < 2; ++tt) {
#pragma unroll
      for (int s = 0; s < 4; ++s) {
        f32x4 m4 = *reinterpret_cast<const f32x4*>(&Ms[kb0 + 32 * tt + 8 * s + 4 * h]);
#pragma unroll
        for (int r = 0; r < 4; ++r) sacc[tt][s * 4 + r] = m4[r];
      }
    }

    // S^T = K * Q^T (2 kv-tiles x 4 d-steps)
    __builtin_amdgcn_s_setprio(1);
#pragma unroll
    for (int tt = 0; tt < 2; ++tt) {
      const int row = 32 * tt + q;
      const int rsw = (row & 7) << 4;
#pragma unroll
      for (int s = 0; s < 4; ++s) {
        bf16x8 kf = *reinterpret_cast<const bf16x8*>(ksb + row * 128 + ((32 * s + 16 * h) ^ rsw));
        sacc[tt] = __builtin_amdgcn_mfma_f32_32x32x16_bf16(kf, qf[s], sacc[tt], 0, 0, 0);
      }
    }
    __builtin_amdgcn_s_setprio(0);

    // exp2 (unnormalized, static-max) + per-lane partial row sums
    float pe[2][16];
#pragma unroll
    for (int tt = 0; tt < 2; ++tt)
#pragma unroll
      for (int i = 0; i < 16; ++i) {
        pe[tt][i] = fexp2(sacc[tt][i]);
        psum4[i & 3] += pe[tt][i];
      }

    // pack P to bf16 B-frags in registers. swap(dst=w0,src=w1): dst[32:63]<->src[0:31].
    u32x4 pw[4];
#pragma unroll
    for (int m = 0; m < 4; ++m) {
      const int tt = m >> 1, mi = (m & 1) * 8;
      u32 w0a = cvtpk_bf16(pe[tt][mi + 0], pe[tt][mi + 1]);
      u32 w0b = cvtpk_bf16(pe[tt][mi + 2], pe[tt][mi + 3]);
      u32 w1a = cvtpk_bf16(pe[tt][mi + 4], pe[tt][mi + 5]);
      u32 w1b = cvtpk_bf16(pe[tt][mi + 6], pe[tt][mi + 7]);
      asm("v_permlane32_swap_b32 %0, %1" : "+v"(w0a), "+v"(w1a));
      asm("v_permlane32_swap_b32 %0, %1" : "+v"(w0b), "+v"(w1b));
      pw[m][0] = w0a; pw[m][1] = w0b; pw[m][2] = w1a; pw[m][3] = w1b;
    }

    // O^T += V^T * P (2 d-tiles x 4 kv-steps)
    __builtin_amdgcn_s_setprio(1);
#pragma unroll
    for (int td = 0; td < 2; ++td) {
      const int row = 32 * td + q;
      const int rsw = (row & 7) << 4;
#pragma unroll
      for (int m = 0; m < 4; ++m) {
        bf16x8 vf = *reinterpret_cast<const bf16x8*>(vsb + row * 128 + ((32 * m + 16 * h) ^ rsw));
        bf16x8 pf = __builtin_bit_cast(bf16x8, pw[m]);
        accT[td] = __builtin_amdgcn_mfma_f32_32x32x16_bf16(vf, pf, accT[td], 0, 0, 0);
      }
    }
    __builtin_amdgcn_s_setprio(0);

    __syncthreads();
  }

  // epilogue: row-sum reduce (l <-> l^32), normalize, transpose via retired Ks buffer
  float l = (psum4[0] + psum4[1]) + (psum4[2] + psum4[3]);
  l += __shfl_xor(l, 32);
  const float inv = 1.0f / l;

  char* slab = (char*)&Ks[0][0][0] + wave * 4096;   // per-wave [32 q][64 d] bf16, swizzled
  const int qsw = (q & 7) << 4;
#pragma unroll
  for (int td = 0; td < 2; ++td)
#pragma unroll
    for (int s = 0; s < 4; ++s) {
      bf16x4 o4;
#pragma unroll
      for (int r = 0; r < 4; ++r) o4[r] = (bf16)(accT[td][s * 4 + r] * inv);
      *reinterpret_cast<bf16x4*>(slab + q * 128 + (((32 * td + 8 * s + 4 * h) * 2) ^ qsw)) = o4;
    }
  asm volatile("s_waitcnt lgkmcnt(0)" ::: "memory");
#pragma unroll
  for (int i = 0; i < 4; ++i) {
    const int row = i * 8 + (lane >> 3);
    bf16x8 v = *reinterpret_cast<const bf16x8*>(slab + row * 128 + (((lane & 7) << 4) ^ ((row & 7) << 4)));
    *reinterpret_cast<bf16x8*>(&Out[((size_t)(b * SEQ) + q0w + row) * Hdim + hh * 64 + (lane & 7) * 8]) = v;
  }
}

// ---------------- output NT-GEMM: 128x64 tile, BK=32, 3-buf counted-vmcnt pipeline ----------------
__global__ __launch_bounds__(256) void out_gemm_k(
    const bf16* __restrict__ A, const bf16* __restrict__ Bm,
    const float* __restrict__ bias, float* __restrict__ C)
{
  __shared__ __align__(16) bf16 As[3][128][32];
  __shared__ __align__(16) bf16 Bs[3][64][32];

  const int t = threadIdx.x;
  const int lane = t & 63, wave = t >> 6;
  const int ql = lane & 15, g = lane >> 4;
  const int wr = wave >> 1, wc = wave & 1;
  const int row0 = blockIdx.x * 128;
  const int col0 = blockIdx.y * 64;

  f32x4 acc[4][2] = {};

#define STAGE_OUT(buf, kt)                                                        \
  {                                                                               \
    _Pragma("unroll")                                                             \
    for (int i = 0; i < 2; ++i) {                                                 \
      int c = i * 256 + t;                                                        \
      int r = c >> 2, o = (c & 3) << 3;                                           \
      gld16(&A[(size_t)(row0 + r) * Hdim + (kt) + o], (char*)&As[buf][0][0] + c * 16); \
    }                                                                             \
    {                                                                             \
      int c = t;                                                                  \
      int r = c >> 2, o = (c & 3) << 3;                                           \
      gld16(&Bm[(size_t)(col0 + r) * Hdim + (kt) + o], (char*)&Bs[buf][0][0] + c * 16); \
    }                                                                             \
  }

  constexpr int NT = Hdim / 32;   // 32 K-steps
  STAGE_OUT(0, 0);
  STAGE_OUT(1, 32);

  int cur = 0;
  for (int it = 0; it < NT; ++it) {
    if (it + 2 < NT) {
      int stg = cur + 2; if (stg >= 3) stg -= 3;
      STAGE_OUT(stg, (it + 2) * 32);
      asm volatile("s_waitcnt vmcnt(6)" ::: "memory");
    } else if (it + 1 < NT) {
      asm volatile("s_waitcnt vmcnt(3)" ::: "memory");
    } else {
      asm volatile("s_waitcnt vmcnt(0)" ::: "memory");
    }
    __builtin_amdgcn_s_barrier();

    bf16x8 af[4], bfr[2];
#pragma unroll
    for (int m = 0; m < 4; ++m)
      af[m] = *reinterpret_cast<const bf16x8*>(&As[cur][wr * 64 + m * 16 + ql][g * 8]);
#pragma unroll
    for (int n = 0; n < 2; ++n)
      bfr[n] = *reinterpret_cast<const bf16x8*>(&Bs[cur][wc * 32 + n * 16 + ql][g * 8]);
#pragma unroll
    for (int m = 0; m < 4; ++m)
#pragma unroll
      for (int n = 0; n < 2; ++n)
        acc[m][n] = __builtin_amdgcn_mfma_f32_16x16x32_bf16(af[m], bfr[n], acc[m][n], 0, 0, 0);

    __builtin_amdgcn_s_barrier();
    cur = (cur + 1 == 3) ? 0 : cur + 1;
  }
#undef STAGE_OUT

#pragma unroll
  for (int m = 0; m < 4; ++m)
#pragma unroll
    for (int n = 0; n < 2; ++n)
#pragma unroll
      for (int r = 0; r < 4; ++r) {
        int gi = row0 + wr * 64 + m * 16 + g * 4 + r;
        int gj = col0 + wc * 32 + n * 16 + ql;
        C[(size_t)gi * Hdim + gj] = acc[m][n][r] + bias[gj];
      }
}

extern "C" void kernel_launch(void* const* d_in, const int* in_sizes, int n_in,
                              void* d_out, int out_size, void* d_ws, size_t ws_size,
                              hipStream_t stream) {
  const float* x    = (const float*)d_in[0];
  const float* mask = (const float*)d_in[1];
  const float* Wq   = (const float*)d_in[2];
  const float* bq   = (const float*)d_in[3];
  const float* Wk   = (const float*)d_in[4];
  const float* bk   = (const float*)d_in[5];
  const float* Wv   = (const float*)d_in[6];
  const float* bv   = (const float*)d_in[7];
  const float* Wo   = (const float*)d_in[8];
  const float* bo   = (const float*)d_in[9];
  float* out = (float*)d_out;

  bf16* xb   = (bf16*)d_ws;
  const size_t big = (size_t)MR * Hdim;       // 4M elems
  bf16* wqkv = xb + big;                      // [3072][1024]
  bf16* wob  = wqkv + (size_t)3 * Hdim * Hdim;
  bf16* qw   = wob + (size_t)Hdim * Hdim;
  bf16* kw   = qw + big;
  bf16* vtw  = kw + big;
  bf16* attnb = vtw + big;
  float* maskS = (float*)(attnb + big);       // [2][2048] f32, pre-scaled by log2e

  const int nslots = MR * Hdim / 8 + 4 * (Hdim * Hdim / 8) + NB * SEQ / 8;  // 1049088
  cvt_all_k<<<nslots / 256, 256, 0, stream>>>(x, Wq, Wk, Wv, Wo, mask, xb, wqkv, wob, maskS);

  qkv_gemm_k<<<dim3(32, 48), 256, 0, stream>>>(
      xb, wqkv, bq, bk, bv, qw, kw, vtw);

  attn_fwd_k<<<dim3(NB * NHEAD, SEQ / 128), 256, 0, stream>>>(qw, kw, vtw, maskS, attnb);

  out_gemm_k<<<dim3(MR / 128, Hdim / 64), 256, 0, stream>>>(attnb, wob, bo, out);
}

// Round 16
// 118.085 us; speedup vs baseline: 1.2506x; 1.0827x over previous
//
#include <hip/hip_runtime.h>

typedef __bf16 bf16;
typedef __bf16 bf16x8 __attribute__((ext_vector_type(8)));
typedef __bf16 bf16x4 __attribute__((ext_vector_type(4)));
typedef float f32x4 __attribute__((ext_vector_type(4)));
typedef float f32x16 __attribute__((ext_vector_type(16)));
typedef unsigned int u32;
typedef u32 u32x4 __attribute__((ext_vector_type(4)));
typedef const u32 __attribute__((address_space(1)))* gp1_t;
typedef u32 __attribute__((address_space(3)))* lp3_t;

constexpr int Hdim = 1024;
constexpr int SEQ  = 2048;
constexpr int NB   = 2;
constexpr int NHEAD = 16;
constexpr int DHEAD = 64;
constexpr int MR = NB * SEQ;   // 4096 rows
constexpr float LOG2E = 1.4426950408889634f;
constexpr float QSCALE = 0.125f * LOG2E;   // folded into Q at projection time

__device__ __forceinline__ float fexp2(float x) { return __builtin_amdgcn_exp2f(x); }

__device__ __forceinline__ void gld16(const void* g, void* l) {
  __builtin_amdgcn_global_load_lds((gp1_t)g, (lp3_t)l, 16, 0, 0);
}

__device__ __forceinline__ u32 cvtpk_bf16(float lo, float hi) {
  u32 r;
  asm("v_cvt_pk_bf16_f32 %0, %1, %2" : "=v"(r) : "v"(lo), "v"(hi));
  return r;
}

// ---------------- fused fp32 -> bf16 convert for x + weights, + scaled mask ----------------
__global__ __launch_bounds__(256) void cvt_all_k(
    const float* __restrict__ x, const float* __restrict__ Wq, const float* __restrict__ Wk,
    const float* __restrict__ Wv, const float* __restrict__ Wo, const float* __restrict__ mask,
    bf16* __restrict__ xb, bf16* __restrict__ wqkv, bf16* __restrict__ wob,
    float* __restrict__ maskS) {
  const int n8x = MR * Hdim / 8;      // 524288
  const int n8w = Hdim * Hdim / 8;    // 131072
  int i = blockIdx.x * 256 + threadIdx.x;
  if (i >= n8x + 4 * n8w) {
    int o = i - (n8x + 4 * n8w);      // [0,512)
    const float4* p = reinterpret_cast<const float4*>(mask) + (size_t)o * 2;
    float4 a = p[0], b = p[1];
    a.x *= LOG2E; a.y *= LOG2E; a.z *= LOG2E; a.w *= LOG2E;
    b.x *= LOG2E; b.y *= LOG2E; b.z *= LOG2E; b.w *= LOG2E;
    float4* q = reinterpret_cast<float4*>(maskS) + (size_t)o * 2;
    q[0] = a; q[1] = b;
    return;
  }
  const float* src;
  bf16* dst;
  int slot;
  if (i < n8x) {
    src = x; dst = xb; slot = i;
  } else {
    int j = i - n8x;
    int w = j >> 17;
    int o = j & (n8w - 1);
    if (w == 0)      { src = Wq; dst = wqkv;            }
    else if (w == 1) { src = Wk; dst = wqkv + (size_t)Hdim * Hdim;     }
    else if (w == 2) { src = Wv; dst = wqkv + (size_t)2 * Hdim * Hdim; }
    else             { src = Wo; dst = wob;             }
    slot = o;
  }
  const float4* p = reinterpret_cast<const float4*>(src) + (size_t)slot * 2;
  float4 a = p[0], b = p[1];
  bf16x8 o8;
  o8[0] = (bf16)a.x; o8[1] = (bf16)a.y; o8[2] = (bf16)a.z; o8[3] = (bf16)a.w;
  o8[4] = (bf16)b.x; o8[5] = (bf16)b.y; o8[6] = (bf16)b.z; o8[7] = (bf16)b.w;
  reinterpret_cast<bf16x8*>(dst)[slot] = o8;
}

// ---------------- fused QKV NT-GEMM: 128x128, BK=32, 3-buf counted-vmcnt, swizzled LDS ----------------
// Swizzle: 16B slot s of row r stored at s^((r>>1)&3)  -> frag reads 2-way (free) vs 8-way.
__global__ __launch_bounds__(256) void qkv_gemm_k(
    const bf16* __restrict__ A, const bf16* __restrict__ Bw,
    const float* __restrict__ bq, const float* __restrict__ bk, const float* __restrict__ bv,
    bf16* __restrict__ Qw, bf16* __restrict__ Kw, bf16* __restrict__ VTw)
{
  __shared__ __align__(16) bf16 As[3][128][32];
  __shared__ __align__(16) bf16 Bs[3][128][32];

  const int t = threadIdx.x;
  const int lane = t & 63, wave = t >> 6;
  const int ql = lane & 15, g = lane >> 4;
  const int wr = wave >> 1, wc = wave & 1;
  const int row0 = blockIdx.x * 128;
  const int col0 = blockIdx.y * 128;
  const int z = blockIdx.y >> 3;
  const float* bias = (z == 0) ? bq : (z == 1) ? bk : bv;
  const int rsl = (g ^ ((ql >> 1) & 3)) * 8;   // swizzled read slot (elems)

  f32x4 acc[4][4] = {};

#define STAGE_QKV(buf, kt)                                                        \
  {                                                                               \
    _Pragma("unroll")                                                             \
    for (int i = 0; i < 2; ++i) {                                                 \
      int c = i * 256 + t;                                                        \
      int r = c >> 2, sp = c & 3;                                                 \
      int sl = (sp ^ ((r >> 1) & 3)) << 3;                                        \
      gld16(&A[(size_t)(row0 + r) * Hdim + (kt) + sl], (char*)&As[buf][0][0] + c * 16); \
      gld16(&Bw[(size_t)(col0 + r) * Hdim + (kt) + sl], (char*)&Bs[buf][0][0] + c * 16); \
    }                                                                             \
  }

  constexpr int NT = Hdim / 32;   // 32 K-steps
  STAGE_QKV(0, 0);
  STAGE_QKV(1, 32);

  int cur = 0;
  for (int it = 0; it < NT; ++it) {
    if (it + 2 < NT) {
      int stg = cur + 2; if (stg >= 3) stg -= 3;
      STAGE_QKV(stg, (it + 2) * 32);
      asm volatile("s_waitcnt vmcnt(8)" ::: "memory");
    } else if (it + 1 < NT) {
      asm volatile("s_waitcnt vmcnt(4)" ::: "memory");
    } else {
      asm volatile("s_waitcnt vmcnt(0)" ::: "memory");
    }
    __builtin_amdgcn_s_barrier();

    bf16x8 af[4], bfr[4];
#pragma unroll
    for (int m = 0; m < 4; ++m)
      af[m] = *reinterpret_cast<const bf16x8*>(&As[cur][wr * 64 + m * 16 + ql][rsl]);
#pragma unroll
    for (int n = 0; n < 4; ++n)
      bfr[n] = *reinterpret_cast<const bf16x8*>(&Bs[cur][wc * 64 + n * 16 + ql][rsl]);
#pragma unroll
    for (int m = 0; m < 4; ++m)
#pragma unroll
      for (int n = 0; n < 4; ++n)
        acc[m][n] = __builtin_amdgcn_mfma_f32_16x16x32_bf16(af[m], bfr[n], acc[m][n], 0, 0, 0);

    __builtin_amdgcn_s_barrier();
    cur = (cur + 1 == 3) ? 0 : cur + 1;
  }
#undef STAGE_QKV

  const float oscale = (z == 0) ? QSCALE : 1.0f;
#pragma unroll
  for (int m = 0; m < 4; ++m) {
#pragma unroll
    for (int n = 0; n < 4; ++n) {
#pragma unroll
      for (int r = 0; r < 4; ++r) {
        int gi = row0 + wr * 64 + m * 16 + g * 4 + r;
        int gj = col0 + wc * 64 + n * 16 + ql;
        int j1 = gj & (Hdim - 1);
        float v = (acc[m][n][r] + bias[j1]) * oscale;
        int b = gi >> 11, s = gi & (SEQ - 1);
        int hh = j1 >> 6, dd = j1 & 63;
        if (z == 0)
          Qw[((size_t)(b * NHEAD + hh) * SEQ + s) * DHEAD + dd] = (bf16)v;
        else if (z == 1)
          Kw[((size_t)(b * NHEAD + hh) * SEQ + s) * DHEAD + dd] = (bf16)v;
        else
          VTw[((size_t)(b * NHEAD + hh) * DHEAD + dd) * SEQ + s] = (bf16)v;
      }
    }
  }
}

// ---------------- flash attention: 32x32 MFMA, in-reg P, 3-buf counted-vmcnt, mask-in-LDS ----------------
// grid: (32 heads, 16 q-tiles of 128). 4 waves x 32 q-rows (q = lane&31, h = lane>>5).
// Raw s_barrier + vmcnt(4) keeps the tile-(t+2) prefetch in flight ACROSS the barrier
// (the old __syncthreads forced a full vmcnt(0) drain every iteration).
__global__ __launch_bounds__(256, 2) void attn_fwd_k(
    const bf16* __restrict__ Q, const bf16* __restrict__ K,
    const bf16* __restrict__ VT, const float* __restrict__ maskS,
    bf16* __restrict__ Out)
{
  const int head = blockIdx.x;
  const int qt = blockIdx.y;
  const int b = head >> 4;
  const int hh = head & 15;
  const int t = threadIdx.x, lane = t & 63, wave = t >> 6;
  const int q = lane & 31, h = lane >> 5;

  __shared__ __align__(16) bf16 Ks[3][64][64];   // [kv][d], xor-swizzled (slot ^= row&7)
  __shared__ __align__(16) bf16 VTs[3][64][64];  // [d][kv], xor-swizzled
  __shared__ __align__(16) float Ms[SEQ];        // pre-scaled mask row, broadcast reads

  const bf16* Qh  = Q  + (size_t)head * SEQ * DHEAD;
  const bf16* Kh  = K  + (size_t)head * SEQ * DHEAD;
  const bf16* VTh = VT + (size_t)head * DHEAD * SEQ;
  const float* mrow = maskS + (size_t)b * SEQ;

  const int q0w = qt * 128 + wave * 32;

  bf16x8 qf[4];
#pragma unroll
  for (int s = 0; s < 4; ++s)
    qf[s] = *reinterpret_cast<const bf16x8*>(&Qh[(size_t)(q0w + q) * DHEAD + s * 16 + 8 * h]);

  f32x16 accT[2] = {};
  f32x4 psum4 = {0.f, 0.f, 0.f, 0.f};

#define STAGE_KV(buf, tile)                                                       \
  {                                                                               \
    const int nb0 = (tile) * 64;                                                  \
    _Pragma("unroll")                                                             \
    for (int i = 0; i < 2; ++i) {                                                 \
      int c = i * 256 + t, r = c >> 3, sp = c & 7, sl = sp ^ (r & 7);             \
      gld16(&Kh[(size_t)(nb0 + r) * DHEAD + sl * 8], (char*)&Ks[buf][0][0] + c * 16); \
      gld16(&VTh[(size_t)r * SEQ + nb0 + sl * 8], (char*)&VTs[buf][0][0] + c * 16);   \
    }                                                                             \
  }

  constexpr int NT = SEQ / 64;   // 32
  // prologue: mask (2 loads, oldest) -> tile0 (4) -> tile1 (4); wait mask+tile0
#pragma unroll
  for (int i = 0; i < 2; ++i) {
    int c = i * 256 + t;
    gld16(&mrow[c * 4], (char*)&Ms[0] + c * 16);
  }
  STAGE_KV(0, 0);
  STAGE_KV(1, 1);
  asm volatile("s_waitcnt vmcnt(4)" ::: "memory");
  __builtin_amdgcn_s_barrier();

  int cur = 0;
  for (int it = 0; it < NT; ++it) {
    if (it + 2 < NT) {
      int stg = cur + 2; if (stg >= 3) stg -= 3;
      STAGE_KV(stg, it + 2);
    }

    const char* ksb = (const char*)&Ks[cur][0][0];
    const char* vsb = (const char*)&VTs[cur][0][0];
    const int kb0 = it * 64;

    // mask as accumulator init (LDS broadcast): reg r+4s of tile tt = kv 32tt+r+8s+4h
    f32x16 sacc[2];
#pragma unroll
    for (int tt = 0; tt < 2; ++tt) {
#pragma unroll
      for (int s = 0; s < 4; ++s) {
        f32x4 m4 = *reinterpret_cast<const f32x4*>(&Ms[kb0 + 32 * tt + 8 * s + 4 * h]);
#pragma unroll
        for (int r = 0; r < 4; ++r) sacc[tt][s * 4 + r] = m4[r];
      }
    }

    // S^T = K * Q^T (2 kv-tiles x 4 d-steps)
    __builtin_amdgcn_s_setprio(1);
#pragma unroll
    for (int tt = 0; tt < 2; ++tt) {
      const int row = 32 * tt + q;
      const int rsw = (row & 7) << 4;
#pragma unroll
      for (int s = 0; s < 4; ++s) {
        bf16x8 kf = *reinterpret_cast<const bf16x8*>(ksb + row * 128 + ((32 * s + 16 * h) ^ rsw));
        sacc[tt] = __builtin_amdgcn_mfma_f32_32x32x16_bf16(kf, qf[s], sacc[tt], 0, 0, 0);
      }
    }
    __builtin_amdgcn_s_setprio(0);

    // exp2 (unnormalized, static-max) + per-lane partial row sums
    float pe[2][16];
#pragma unroll
    for (int tt = 0; tt < 2; ++tt)
#pragma unroll
      for (int i = 0; i < 16; ++i) {
        pe[tt][i] = fexp2(sacc[tt][i]);
        psum4[i & 3] += pe[tt][i];
      }

    // pack P to bf16 B-frags in registers. swap(dst=w0,src=w1): dst[32:63]<->src[0:31].
    u32x4 pw[4];
#pragma unroll
    for (int m = 0; m < 4; ++m) {
      const int tt = m >> 1, mi = (m & 1) * 8;
      u32 w0a = cvtpk_bf16(pe[tt][mi + 0], pe[tt][mi + 1]);
      u32 w0b = cvtpk_bf16(pe[tt][mi + 2], pe[tt][mi + 3]);
      u32 w1a = cvtpk_bf16(pe[tt][mi + 4], pe[tt][mi + 5]);
      u32 w1b = cvtpk_bf16(pe[tt][mi + 6], pe[tt][mi + 7]);
      asm("v_permlane32_swap_b32 %0, %1" : "+v"(w0a), "+v"(w1a));
      asm("v_permlane32_swap_b32 %0, %1" : "+v"(w0b), "+v"(w1b));
      pw[m][0] = w0a; pw[m][1] = w0b; pw[m][2] = w1a; pw[m][3] = w1b;
    }

    // O^T += V^T * P (2 d-tiles x 4 kv-steps)
    __builtin_amdgcn_s_setprio(1);
#pragma unroll
    for (int td = 0; td < 2; ++td) {
      const int row = 32 * td + q;
      const int rsw = (row & 7) << 4;
#pragma unroll
      for (int m = 0; m < 4; ++m) {
        bf16x8 vf = *reinterpret_cast<const bf16x8*>(vsb + row * 128 + ((32 * m + 16 * h) ^ rsw));
        bf16x8 pf = __builtin_bit_cast(bf16x8, pw[m]);
        accT[td] = __builtin_amdgcn_mfma_f32_32x32x16_bf16(vf, pf, accT[td], 0, 0, 0);
      }
    }
    __builtin_amdgcn_s_setprio(0);

    // counted drain: tile it+1 must be resident; keep it+2 in flight across barrier
    if (it + 2 < NT)      asm volatile("s_waitcnt vmcnt(4)" ::: "memory");
    else if (it + 1 < NT) asm volatile("s_waitcnt vmcnt(0)" ::: "memory");
    __builtin_amdgcn_s_barrier();
    cur = (cur + 1 == 3) ? 0 : cur + 1;
  }
#undef STAGE_KV

  // epilogue: row-sum reduce (l <-> l^32), normalize, transpose via retired Ks[0]
  float l = (psum4[0] + psum4[1]) + (psum4[2] + psum4[3]);
  l += __shfl_xor(l, 32);
  const float inv = 1.0f / l;

  char* slab = (char*)&Ks[0][0][0] + wave * 4096;   // per-wave [32 q][64 d] bf16, swizzled
  const int qsw = (q & 7) << 4;
#pragma unroll
  for (int td = 0; td < 2; ++td)
#pragma unroll
    for (int s = 0; s < 4; ++s) {
      bf16x4 o4;
#pragma unroll
      for (int r = 0; r < 4; ++r) o4[r] = (bf16)(accT[td][s * 4 + r] * inv);
      *reinterpret_cast<bf16x4*>(slab + q * 128 + (((32 * td + 8 * s + 4 * h) * 2) ^ qsw)) = o4;
    }
  asm volatile("s_waitcnt lgkmcnt(0)" ::: "memory");
#pragma unroll
  for (int i = 0; i < 4; ++i) {
    const int row = i * 8 + (lane >> 3);
    bf16x8 v = *reinterpret_cast<const bf16x8*>(slab + row * 128 + (((lane & 7) << 4) ^ ((row & 7) << 4)));
    *reinterpret_cast<bf16x8*>(&Out[((size_t)(b * SEQ) + q0w + row) * Hdim + hh * 64 + (lane & 7) * 8]) = v;
  }
}

// ---------------- output NT-GEMM: 128x64, BK=32, 3-buf counted-vmcnt, swizzled LDS ----------------
__global__ __launch_bounds__(256) void out_gemm_k(
    const bf16* __restrict__ A, const bf16* __restrict__ Bm,
    const float* __restrict__ bias, float* __restrict__ C)
{
  __shared__ __align__(16) bf16 As[3][128][32];
  __shared__ __align__(16) bf16 Bs[3][64][32];

  const int t = threadIdx.x;
  const int lane = t & 63, wave = t >> 6;
  const int ql = lane & 15, g = lane >> 4;
  const int wr = wave >> 1, wc = wave & 1;
  const int row0 = blockIdx.x * 128;
  const int col0 = blockIdx.y * 64;
  const int rsl = (g ^ ((ql >> 1) & 3)) * 8;

  f32x4 acc[4][2] = {};

#define STAGE_OUT(buf, kt)                                                        \
  {                                                                               \
    _Pragma("unroll")                                                             \
    for (int i = 0; i < 2; ++i) {                                                 \
      int c = i * 256 + t;                                                        \
      int r = c >> 2, sp = c & 3;                                                 \
      int sl = (sp ^ ((r >> 1) & 3)) << 3;                                        \
      gld16(&A[(size_t)(row0 + r) * Hdim + (kt) + sl], (char*)&As[buf][0][0] + c * 16); \
    }                                                                             \
    {                                                                             \
      int c = t;                                                                  \
      int r = c >> 2, sp = c & 3;                                                 \
      int sl = (sp ^ ((r >> 1) & 3)) << 3;                                        \
      gld16(&Bm[(size_t)(col0 + r) * Hdim + (kt) + sl], (char*)&Bs[buf][0][0] + c * 16); \
    }                                                                             \
  }

  constexpr int NT = Hdim / 32;   // 32 K-steps
  STAGE_OUT(0, 0);
  STAGE_OUT(1, 32);

  int cur = 0;
  for (int it = 0; it < NT; ++it) {
    if (it + 2 < NT) {
      int stg = cur + 2; if (stg >= 3) stg -= 3;
      STAGE_OUT(stg, (it + 2) * 32);
      asm volatile("s_waitcnt vmcnt(6)" ::: "memory");
    } else if (it + 1 < NT) {
      asm volatile("s_waitcnt vmcnt(3)" ::: "memory");
    } else {
      asm volatile("s_waitcnt vmcnt(0)" ::: "memory");
    }
    __builtin_amdgcn_s_barrier();

    bf16x8 af[4], bfr[2];
#pragma unroll
    for (int m = 0; m < 4; ++m)
      af[m] = *reinterpret_cast<const bf16x8*>(&As[cur][wr * 64 + m * 16 + ql][rsl]);
#pragma unroll
    for (int n = 0; n < 2; ++n)
      bfr[n] = *reinterpret_cast<const bf16x8*>(&Bs[cur][wc * 32 + n * 16 + ql][rsl]);
#pragma unroll
    for (int m = 0; m < 4; ++m)
#pragma unroll
      for (int n = 0; n < 2; ++n)
        acc[m][n] = __builtin_amdgcn_mfma_f32_16x16x32_bf16(af[m], bfr[n], acc[m][n], 0, 0, 0);

    __builtin_amdgcn_s_barrier();
    cur = (cur + 1 == 3) ? 0 : cur + 1;
  }
#undef STAGE_OUT

#pragma unroll
  for (int m = 0; m < 4; ++m)
#pragma unroll
    for (int n = 0; n < 2; ++n)
#pragma unroll
      for (int r = 0; r < 4; ++r) {
        int gi = row0 + wr * 64 + m * 16 + g * 4 + r;
        int gj = col0 + wc * 32 + n * 16 + ql;
        C[(size_t)gi * Hdim + gj] = acc[m][n][r] + bias[gj];
      }
}

extern "C" void kernel_launch(void* const* d_in, const int* in_sizes, int n_in,
                              void* d_out, int out_size, void* d_ws, size_t ws_size,
                              hipStream_t stream) {
  const float* x    = (const float*)d_in[0];
  const float* mask = (const float*)d_in[1];
  const float* Wq   = (const float*)d_in[2];
  const float* bq   = (const float*)d_in[3];
  const float* Wk   = (const float*)d_in[4];
  const float* bk   = (const float*)d_in[5];
  const float* Wv   = (const float*)d_in[6];
  const float* bv   = (const float*)d_in[7];
  const float* Wo   = (const float*)d_in[8];
  const float* bo   = (const float*)d_in[9];
  float* out = (float*)d_out;

  bf16* xb   = (bf16*)d_ws;
  const size_t big = (size_t)MR * Hdim;       // 4M elems
  bf16* wqkv = xb + big;                      // [3072][1024]
  bf16* wob  = wqkv + (size_t)3 * Hdim * Hdim;
  bf16* qw   = wob + (size_t)Hdim * Hdim;
  bf16* kw   = qw + big;
  bf16* vtw  = kw + big;
  bf16* attnb = vtw + big;
  float* maskS = (float*)(attnb + big);       // [2][2048] f32, pre-scaled by log2e

  const int nslots = MR * Hdim / 8 + 4 * (Hdim * Hdim / 8) + NB * SEQ / 8;  // 1049088
  cvt_all_k<<<nslots / 256, 256, 0, stream>>>(x, Wq, Wk, Wv, Wo, mask, xb, wqkv, wob, maskS);

  qkv_gemm_k<<<dim3(MR / 128, 3 * Hdim / 128), 256, 0, stream>>>(
      xb, wqkv, bq, bk, bv, qw, kw, vtw);

  attn_fwd_k<<<dim3(NB * NHEAD, SEQ / 128), 256, 0, stream>>>(qw, kw, vtw, maskS, attnb);

  out_gemm_k<<<dim3(MR / 128, Hdim / 64), 256, 0, stream>>>(attnb, wob, bo, out);
}